// Round 5
// baseline (129.941 us; speedup 1.0000x reference)
//
#include <hip/hip_runtime.h>
#include <hip/hip_bf16.h>

typedef unsigned short ushort_t;
typedef unsigned int uint_t;

#define CIN   128
#define COUT  256
#define HH    56
#define WW    56
#define HWSZ  3136            // 56*56
#define BATCH 16
#define NPIX  50176           // 16*3136
#define KTOT  1152            // 128*9

typedef __attribute__((ext_vector_type(8))) short bf16x8;
typedef __attribute__((ext_vector_type(4))) float f32x4;

__device__ __forceinline__ ushort_t f2bf(float v) {
    union { float f; uint_t u; } c; c.f = v;
    uint_t u = c.u;
    u += 0x7FFFu + ((u >> 16) & 1u);   // RNE; inputs finite
    return (ushort_t)(u >> 16);
}

__device__ __forceinline__ uint_t pk2bf(float lo, float hi) {
    __hip_bfloat162 h = __float22bfloat162_rn(make_float2(lo, hi));  // x->low, y->high
    union { __hip_bfloat162 h; uint_t u; } c; c.h = h;
    return c.u;
}

// ---- fused prepass:
//  blocks [0,784):   input NCHW fp32 -> NHWC bf16 (64hw x 128ci tile, 2x2 reg transpose,
//                    packed bf16 cvt, XOR-swizzled b32 LDS writes -> conflict-free)
//  blocks [784,1040): weight OIHW fp32 -> A2 fragment-order table:
//                    A2[((mt*36+s)*4+i)*64 + quad*16 + l16] = ushort8 of
//                    W[co = mt*64+i*16+l16][k = s*32+quad*8 .. +8], k=(pos,ci) order.
//                    conv_gemm then loads A frags as coalesced global dwordx4 (no LDS).
//  block 784 zeroes the 1KB guard page.
__global__ __launch_bounds__(256) void prep(
    const float* __restrict__ tensor, const float* __restrict__ weights,
    ushort_t* __restrict__ Ib, ushort_t* __restrict__ A2, ushort_t* __restrict__ guard)
{
    __shared__ __align__(16) uint_t lds_u[64 * 68];   // 64 hw rows x 68 uints (=128ci + pad)
    const int tid = threadIdx.x;

    if (blockIdx.x < 784) {
        int t   = blockIdx.x;
        int b   = t / 49;
        int hwt = t - b * 49;
        int hw0 = hwt * 64;
        const float* src = tensor + (size_t)b * CIN * HWSZ + hw0;
        // 1024 tasks: hb = hw-block of 4, cp = ci-pair. Loads coalesced (16 lanes x 16B).
        #pragma unroll
        for (int k = 0; k < 4; ++k) {
            int t2 = tid + k * 256;
            int hb = t2 & 15;
            int cp = t2 >> 4;                      // [0,64)
            const float* s0 = src + (size_t)(2 * cp) * HWSZ + hb * 4;
            float4 a  = *(const float4*)s0;
            float4 bb = *(const float4*)(s0 + HWSZ);
            uint_t w0 = pk2bf(a.x, bb.x);
            uint_t w1 = pk2bf(a.y, bb.y);
            uint_t w2 = pk2bf(a.z, bb.z);
            uint_t w3 = pk2bf(a.w, bb.w);
            int c16  = cp >> 2;
            int lb   = cp & 3;
            int c16p = c16 ^ (hb & 7);             // swizzle: row>>2 == hb for all 4 rows
            uint_t* base = &lds_u[(hb * 4) * 68 + c16p * 4 + lb];
            base[0 * 68] = w0;
            base[1 * 68] = w1;
            base[2 * 68] = w2;
            base[3 * 68] = w3;
        }
        __syncthreads();
        ushort_t* dst = Ib + ((size_t)b * HWSZ + hw0) * CIN;
        #pragma unroll
        for (int k = 0; k < 4; ++k) {
            int s2  = tid + k * 256;               // 1024 = 64 rows x 16 chunks
            int ho  = s2 >> 4;
            int c16 = s2 & 15;
            int c16p = c16 ^ ((ho >> 2) & 7);
            uint4 v = *(const uint4*)&lds_u[ho * 68 + c16p * 4];
            *(uint4*)(dst + ho * 128 + c16 * 8) = v;   // coalesced 256B per 16 lanes
        }
    } else {
        int co = blockIdx.x - 784;
        ushort_t* lds_s = (ushort_t*)lds_u;
        const float* src = weights + (size_t)co * KTOT;
        #pragma unroll
        for (int k = 0; k < 5; ++k) {
            int idx = tid + k * 256;
            if (idx < KTOT) {
                int ci  = idx / 9;
                int pos = idx - ci * 9;
                lds_s[pos * 128 + ci] = f2bf(src[idx]);   // coalesced fp32 read
            }
        }
        __syncthreads();
        // emit 144 fragment chunks (s in [0,36), quad in [0,4)) for this co
        int mt  = co >> 6;
        int ii  = (co >> 4) & 3;
        int l16 = co & 15;
        if (tid < 144) {
            int s    = tid >> 2;
            int quad = tid & 3;
            uint4 v = *(const uint4*)&lds_s[(s >> 2) * 128 + (s & 3) * 32 + quad * 8];
            *(uint4*)(A2 + ((size_t)((mt * 36 + s) * 4 + ii) * 64 + quad * 16 + l16) * 8) = v;
        }
        if (blockIdx.x == 784 && tid < 128) ((uint_t*)guard)[tid] = 0;  // 512B zeros
    }
}

// ---- main implicit-GEMM conv: C[co][pix] = sum_k W[co][k] * Ib[shift(pix,pos)][ci]
// Tile 128m x 64n, 2 waves (each 64x64). A fragments stream global->VGPR from the
// pre-swizzled A2 table (coalesced dwordx4, L2-resident 0.59MB) -- no LDS for A.
// Only B goes through LDS (8KB dbuf). One barrier per k32 step; stage s+1 right
// after barrier s. Grid 1568 -> ~6 independent blocks/CU overlap each other's drains.
__global__ __launch_bounds__(128, 3) void conv_gemm(
    const ushort_t* __restrict__ A2,   // fragment-order weights
    const ushort_t* __restrict__ Ib,   // [NPIX][128] bf16 NHWC
    const float* __restrict__ bias,
    float* __restrict__ out,
    const ushort_t* __restrict__ guard)
{
    __shared__ ushort_t B_lds[2][64 * 32];

    const int tid  = threadIdx.x;
    const int wave = tid >> 6;
    const int lane = tid & 63;
    const int quad = lane >> 4;
    const int l16  = lane & 15;

    // XCD pairing: blk j and j+8 land on the same XCD (round-robin); give them the
    // same bn so the B tile is fetched once per XCD.
    const int g  = blockIdx.x >> 4;          // [0,98)
    const int bm = (blockIdx.x >> 3) & 1;    // cout half
    const int bn = g * 8 + (blockIdx.x & 7); // pixel tile [0,784)
    const int mt = bm * 2 + wave;            // 64-row m-group in A2

    // ---- B staging offsets (2 chunks per lane), 32-bit offsets from Ib ----
    int bOff[9][2];
    #pragma unroll
    for (int k = 0; k < 2; ++k) {
        int slot = k * 128 + tid;            // [0,256): covers 64 rows x 4 chunks
        int r  = slot >> 2;
        int c  = slot & 3;
        int cF = c ^ ((r >> 1) & 3);         // fetch-chunk XOR swizzle
        int pix = bn * 64 + r;
        int b_  = pix / HWSZ;
        int rem = pix - b_ * HWSZ;
        int y_  = rem / WW;
        int x_  = rem - y_ * WW;
        int base = pix * CIN + cF * 8;
        int goff = (int)(guard - Ib);
        #pragma unroll
        for (int pos = 0; pos < 9; ++pos) {
            const int dy = pos / 3 - 1;
            const int dx = pos % 3 - 1;
            int yy = y_ + dy, xx = x_ + dx;
            bool ok = ((uint_t)yy < (uint_t)HH) && ((uint_t)xx < (uint_t)WW);
            bOff[pos][k] = ok ? (base + (dy * WW + dx) * CIN) : goff;
        }
    }
    const int xorc = (l16 >> 1) & 3;         // read-side swizzle

    // A fragment stream base: chunk (s*4+i), lane-contiguous 16B
    const ushort_t* aBase = A2 + ((size_t)mt * 36 * 4 * 64 + lane) * 8;

    auto stageB = [&](int s, int buf) {
        const int pos = s >> 2;              // constant after unroll
        const int cc  = s & 3;
        #pragma unroll
        for (int k = 0; k < 2; ++k) {
            __builtin_amdgcn_global_load_lds(
                (const __attribute__((address_space(1))) void*)(Ib + bOff[pos][k] + cc * 32),
                (__attribute__((address_space(3))) void*)(&B_lds[buf][(k * 128 + wave * 64) * 8]),
                16, 0, 0);
        }
    };

    const f32x4 zero = {0.f, 0.f, 0.f, 0.f};
    f32x4 acc[4][4];
    #pragma unroll
    for (int i = 0; i < 4; ++i)
        #pragma unroll
        for (int j = 0; j < 4; ++j) acc[i][j] = zero;

    bf16x8 aCur[4], aNxt[4];
    stageB(0, 0);
    #pragma unroll
    for (int i = 0; i < 4; ++i)
        aCur[i] = *(const bf16x8*)(aBase + (size_t)i * 512);

    #pragma unroll
    for (int s = 0; s < 36; ++s) {
        __syncthreads();                         // B buf (s&1) ready; drains vmem
        if (s < 35) {
            stageB(s + 1, (s + 1) & 1);          // prefetch B: full iteration in flight
            #pragma unroll
            for (int i = 0; i < 4; ++i)          // prefetch A frags for s+1 (regs)
                aNxt[i] = *(const bf16x8*)(aBase + (size_t)((s + 1) * 4 + i) * 512);
        }
        const int p = s & 1;
        bf16x8 bfr[4];
        #pragma unroll
        for (int j = 0; j < 4; ++j)
            bfr[j] = *(const bf16x8*)&B_lds[p][(j * 16 + l16) * 32 + (quad ^ xorc) * 8];
        #pragma unroll
        for (int i = 0; i < 4; ++i)
            #pragma unroll
            for (int j = 0; j < 4; ++j)
                acc[i][j] = __builtin_amdgcn_mfma_f32_16x16x32_bf16(
                    aCur[i], bfr[j], acc[i][j], 0, 0, 0);
        #pragma unroll
        for (int i = 0; i < 4; ++i) aCur[i] = aNxt[i];   // renamed away under unroll
    }

    // epilogue: D row (quad*4+r) = cout, col (lane&15) = pixel (x-contiguous stores)
    int obase[4];
    #pragma unroll
    for (int j = 0; j < 4; ++j) {
        int pix = bn * 64 + j * 16 + l16;
        int b_  = pix / HWSZ;
        int rem = pix - b_ * HWSZ;
        obase[j] = b_ * (COUT * HWSZ) + rem;
    }
    #pragma unroll
    for (int i = 0; i < 4; ++i) {
        #pragma unroll
        for (int r = 0; r < 4; ++r) {
            int co = bm * 128 + wave * 64 + i * 16 + quad * 4 + r;
            float bv = bias[co];
            int coOff = co * HWSZ;
            #pragma unroll
            for (int j = 0; j < 4; ++j) {
                out[(size_t)(obase[j] + coOff)] = acc[i][j][r] + bv;
            }
        }
    }
}

// ---- fallback (only if workspace is too small): direct fp32 conv
__global__ void naive_conv(const float* __restrict__ in, const float* __restrict__ w,
                           const float* __restrict__ bias, float* __restrict__ out, int total) {
    int idx = blockIdx.x * 256 + threadIdx.x;
    if (idx >= total) return;
    int x = idx % WW; int t = idx / WW;
    int y = t % HH; t /= HH;
    int co = t % COUT; int b = t / COUT;
    float s = bias[co];
    const float* wr = w + (size_t)co * KTOT;
    for (int ci = 0; ci < CIN; ++ci) {
        const float* ir = in + (size_t)(b * CIN + ci) * HWSZ;
        for (int kh = 0; kh < 3; ++kh) {
            int yy = y + kh - 1;
            if ((uint_t)yy >= (uint_t)HH) continue;
            for (int kw = 0; kw < 3; ++kw) {
                int xx = x + kw - 1;
                if ((uint_t)xx >= (uint_t)WW) continue;
                s += ir[yy * WW + xx] * wr[ci * 9 + kh * 3 + kw];
            }
        }
    }
    out[idx] = s;
}

extern "C" void kernel_launch(void* const* d_in, const int* in_sizes, int n_in,
                              void* d_out, int out_size, void* d_ws, size_t ws_size,
                              hipStream_t stream) {
    const float* tensor  = (const float*)d_in[0];
    const float* weights = (const float*)d_in[1];
    const float* bias    = (const float*)d_in[2];
    float* out = (float*)d_out;

    const size_t GUARD    = 1024;
    const size_t A2_BYTES = (size_t)COUT * KTOT * 2;   // 589824
    const size_t IB_BYTES = (size_t)NPIX * CIN * 2;    // 12845056
    const size_t NEED     = GUARD + A2_BYTES + IB_BYTES;

    if (ws_size >= NEED) {
        ushort_t* guard = (ushort_t*)d_ws;
        ushort_t* A2    = (ushort_t*)((char*)d_ws + GUARD);
        ushort_t* Ib    = (ushort_t*)((char*)d_ws + GUARD + A2_BYTES);
        prep<<<784 + COUT, 256, 0, stream>>>(tensor, weights, Ib, A2, guard);
        conv_gemm<<<2 * 784, 128, 0, stream>>>(A2, Ib, bias, out, guard);
    } else {
        int total = BATCH * COUT * HWSZ;
        naive_conv<<<(total + 255) / 256, 256, 0, stream>>>(tensor, weights, bias, out, total);
    }
}

// Round 6
// 110.331 us; speedup vs baseline: 1.1777x; 1.1777x over previous
//
#include <hip/hip_runtime.h>
#include <hip/hip_bf16.h>

typedef unsigned short ushort_t;
typedef unsigned int uint_t;

#define CIN   128
#define COUT  256
#define HH    56
#define WW    56
#define HWSZ  3136            // 56*56
#define BATCH 16
#define NPIX  50176           // 16*3136
#define KTOT  1152            // 128*9

// LDS input patch: 4 pixel-rows (y0-1..y0+2) x 58 x-cols (halo) x 128 ci.
// ci-stride = 136 ushorts (68 uints): keeps 16B alignment (136%8==0) and spreads
// banks (272B/row -> bank stride 4 -> b128 reads hit the 8-cyc floor, no extra conflict).
#define PROW_U 68             // uints per (pr,x) cell row of ci
#define PATCH_U (4 * 58 * 68) // 15776 uints = 63104 B

typedef __attribute__((ext_vector_type(8))) short bf16x8;
typedef __attribute__((ext_vector_type(4))) float f32x4;

__device__ __forceinline__ ushort_t f2bf(float v) {
    union { float f; uint_t u; } c; c.f = v;
    uint_t u = c.u;
    u += 0x7FFFu + ((u >> 16) & 1u);   // RNE; inputs finite
    return (ushort_t)(u >> 16);
}

__device__ __forceinline__ uint_t pk2bf(float lo, float hi) {
    __hip_bfloat162 h = __float22bfloat162_rn(make_float2(lo, hi));  // x->low ushort
    union { __hip_bfloat162 h; uint_t u; } c; c.h = h;
    return c.u;
}

// ---- weight prep: OIHW fp32 -> A2 fragment-order table (one co per block).
// A2[((mt*36+s)*4+i)*64 + quad*16 + l16] (ushort8) = W[co=mt*64+i*16+l16][k=s*32+quad*8..+8],
// k in (pos,ci) order. conv reads A frags as coalesced global dwordx4 (L2-resident 0.59MB).
__global__ __launch_bounds__(256) void wprep(
    const float* __restrict__ weights, ushort_t* __restrict__ A2)
{
    __shared__ ushort_t lds_s[KTOT];
    const int tid = threadIdx.x;
    const int co  = blockIdx.x;
    const float* src = weights + (size_t)co * KTOT;
    #pragma unroll
    for (int k = 0; k < 5; ++k) {
        int idx = tid + k * 256;
        if (idx < KTOT) {
            int ci  = idx / 9;
            int pos = idx - ci * 9;
            lds_s[pos * 128 + ci] = f2bf(src[idx]);   // coalesced fp32 read
        }
    }
    __syncthreads();
    int mt  = co >> 6;
    int ii  = (co >> 4) & 3;
    int l16 = co & 15;
    if (tid < 144) {
        int s    = tid >> 2;
        int quad = tid & 3;
        uint4 v = *(const uint4*)&lds_s[(s >> 2) * 128 + (s & 3) * 32 + quad * 8];
        *(uint4*)(A2 + ((size_t)((mt * 36 + s) * 4 + ii) * 64 + quad * 16 + l16) * 8) = v;
    }
}

// ---- direct conv: block = 256co x 112pix (2 rows of one image), 4 waves (64co x 112pix).
// Prologue stages the fp32 input patch to LDS bf16 once (halo zeros included); then a
// fully-unrolled, BARRIER-FREE 36-step K-loop: ds_read_b128 B-frags + global A-frag
// stream + MFMA. No per-step vmcnt(0) drain -- the m97-plateau stall is gone.
__global__ __launch_bounds__(256, 2) void conv_direct(
    const ushort_t* __restrict__ A2,
    const float* __restrict__ tensor,
    const float* __restrict__ bias,
    float* __restrict__ out)
{
    __shared__ __align__(16) uint_t patch[PATCH_U];
    const int tid  = threadIdx.x;
    const int wave = tid >> 6;
    const int lane = tid & 63;
    const int quad = lane >> 4;
    const int l16  = lane & 15;

    const int bn = blockIdx.x;            // [0,448): 28 blocks per image
    const int b  = bn / 28;
    const int y0 = (bn - b * 28) * 2;     // first output row of this block

    // ---- zero-fill LDS (covers halo rows/cols) ----
    #pragma unroll
    for (int k = 0; k < 16; ++k) {
        int i4 = tid + k * 256;           // uint4 granules; need 3944
        if (i4 < PATCH_U / 4) *(uint4*)&patch[i4 * 4] = make_uint4(0u, 0u, 0u, 0u);
    }
    __syncthreads();

    // ---- stage input rows y0-1..y0+2 (fp32 NCHW -> bf16 patch) ----
    // task: pr=row (wave-uniform per it), cp=ci-pair, xq=x-quad; 14 consecutive lanes
    // read 224B contiguous (coalesced); packed cvt -> 4 ds_write_b32.
    const float* src_b = tensor + (size_t)b * CIN * HWSZ;
    #pragma unroll
    for (int it = 0; it < 16; ++it) {
        int xq = tid & 15;
        int t2 = it * 16 + (tid >> 4);    // [0,256)
        int cp = t2 & 63;
        int pr = t2 >> 6;
        int y  = y0 - 1 + pr;
        if (xq < 14 && (uint_t)y < (uint_t)HH) {
            const float* s0 = src_b + (size_t)(2 * cp) * HWSZ + y * WW + xq * 4;
            float4 va = *(const float4*)s0;
            float4 vb = *(const float4*)(s0 + HWSZ);
            uint_t* dst = &patch[(pr * 58 + xq * 4 + 1) * PROW_U + cp];
            dst[0 * PROW_U] = pk2bf(va.x, vb.x);
            dst[1 * PROW_U] = pk2bf(va.y, vb.y);
            dst[2 * PROW_U] = pk2bf(va.z, vb.z);
            dst[3 * PROW_U] = pk2bf(va.w, vb.w);
        }
    }
    __syncthreads();      // the ONLY barrier before the K-loop

    // ---- B-fragment LDS bases (halo-corner per j; quad ci-offset folded in) ----
    const ushort_t* patch_s = (const ushort_t*)patch;
    int bbase[7];
    #pragma unroll
    for (int j = 0; j < 7; ++j) {
        int p  = j * 16 + l16;            // block-local pixel [0,112)
        int ro = p / 56;
        int x  = p - ro * 56;
        bbase[j] = (ro * 58 + x) * 136 + quad * 8;   // ushort idx
    }

    // ---- A fragment stream (global, register dbuf) ----
    const ushort_t* aPtr = A2 + ((size_t)(wave * 144) * 64 + lane) * 8;
    bf16x8 aCur[4], aNxt[4];
    #pragma unroll
    for (int i = 0; i < 4; ++i) aCur[i] = *(const bf16x8*)(aPtr + i * 512);

    const f32x4 zero = {0.f, 0.f, 0.f, 0.f};
    f32x4 acc[4][7];
    #pragma unroll
    for (int i = 0; i < 4; ++i)
        #pragma unroll
        for (int j = 0; j < 7; ++j) acc[i][j] = zero;

    #pragma unroll
    for (int pos = 0; pos < 9; ++pos) {
        const int dy = pos / 3 - 1;
        const int dx = pos % 3 - 1;
        const int poff = ((dy + 1) * 58 + (dx + 1)) * 136;   // compile-time, >=0
        #pragma unroll
        for (int cc = 0; cc < 4; ++cc) {
            const int s = pos * 4 + cc;
            if (s < 35) {
                aPtr += 2048;             // advance one k32-step (4096 B)
                #pragma unroll
                for (int i = 0; i < 4; ++i)
                    aNxt[i] = *(const bf16x8*)(aPtr + i * 512);
            }
            bf16x8 bfr[7];
            #pragma unroll
            for (int j = 0; j < 7; ++j)
                bfr[j] = *(const bf16x8*)&patch_s[bbase[j] + poff + cc * 32];
            #pragma unroll
            for (int i = 0; i < 4; ++i)
                #pragma unroll
                for (int j = 0; j < 7; ++j)
                    acc[i][j] = __builtin_amdgcn_mfma_f32_16x16x32_bf16(
                        aCur[i], bfr[j], acc[i][j], 0, 0, 0);
            #pragma unroll
            for (int i = 0; i < 4; ++i) aCur[i] = aNxt[i];
        }
    }

    // ---- epilogue: row(quad*4+r)=cout, col(l16)=pixel (x-contiguous 64B segments) ----
    int opix[7];
    #pragma unroll
    for (int j = 0; j < 7; ++j) {
        int p  = j * 16 + l16;
        int ro = p / 56;
        int x  = p - ro * 56;
        opix[j] = (y0 + ro) * WW + x;
    }
    const size_t bout = (size_t)b * (COUT * HWSZ);
    #pragma unroll
    for (int i = 0; i < 4; ++i) {
        #pragma unroll
        for (int r = 0; r < 4; ++r) {
            int co = wave * 64 + i * 16 + quad * 4 + r;
            float bv = bias[co];
            size_t obase = bout + (size_t)co * HWSZ;
            #pragma unroll
            for (int j = 0; j < 7; ++j)
                out[obase + opix[j]] = acc[i][j][r] + bv;
        }
    }
}

// ---- fallback (only if workspace is too small): direct fp32 conv
__global__ void naive_conv(const float* __restrict__ in, const float* __restrict__ w,
                           const float* __restrict__ bias, float* __restrict__ out, int total) {
    int idx = blockIdx.x * 256 + threadIdx.x;
    if (idx >= total) return;
    int x = idx % WW; int t = idx / WW;
    int y = t % HH; t /= HH;
    int co = t % COUT; int b = t / COUT;
    float s = bias[co];
    const float* wr = w + (size_t)co * KTOT;
    for (int ci = 0; ci < CIN; ++ci) {
        const float* ir = in + (size_t)(b * CIN + ci) * HWSZ;
        for (int kh = 0; kh < 3; ++kh) {
            int yy = y + kh - 1;
            if ((uint_t)yy >= (uint_t)HH) continue;
            for (int kw = 0; kw < 3; ++kw) {
                int xx = x + kw - 1;
                if ((uint_t)xx >= (uint_t)WW) continue;
                s += ir[yy * WW + xx] * wr[ci * 9 + kh * 3 + kw];
            }
        }
    }
    out[idx] = s;
}

extern "C" void kernel_launch(void* const* d_in, const int* in_sizes, int n_in,
                              void* d_out, int out_size, void* d_ws, size_t ws_size,
                              hipStream_t stream) {
    const float* tensor  = (const float*)d_in[0];
    const float* weights = (const float*)d_in[1];
    const float* bias    = (const float*)d_in[2];
    float* out = (float*)d_out;

    const size_t A2_BYTES = (size_t)COUT * KTOT * 2;   // 589824

    if (ws_size >= A2_BYTES) {
        ushort_t* A2 = (ushort_t*)d_ws;
        wprep<<<COUT, 256, 0, stream>>>(weights, A2);
        conv_direct<<<NPIX / 112, 256, 0, stream>>>(A2, tensor, bias, out);
    } else {
        int total = BATCH * COUT * HWSZ;
        naive_conv<<<(total + 255) / 256, 256, 0, stream>>>(tensor, weights, bias, out, total);
    }
}